// Round 2
// baseline (166.696 us; speedup 1.0000x reference)
//
#include <hip/hip_runtime.h>

// EuclideanLoss: loss = mean_n [ w_n * mean_b sqrt(sum_d (x[b,n,d]-y[b,d,n])^2) ]
// w_n = 1.5 for n in {1,2}. B=32, N=8192, D=64, fp32. Memory-bound, 128 MiB read.
//
// R1: R0 was latency-bound (occupancy 28%, 1.9 TB/s). Split each (b,n) pair's
// D=64 across 4 threads -> 4x wave count (64 waves/CU demanded vs 32 cap) and
// hoist ALL loads (4x float4 + 16 scalar) before any FMA for max MLP.

constexpr int B = 32;
constexpr int N = 8192;
constexpr int D = 64;
constexpr int TPP = 4;          // threads per (b,n) pair
constexpr int DC  = D / TPP;    // 16 d-elements per thread
constexpr int PAIRS_PER_BLOCK = 256 / TPP;  // 64

__global__ __launch_bounds__(256) void euclid_loss_kernel(
    const float* __restrict__ x,   // [B, N, D]
    const float* __restrict__ y,   // [B, D, N]
    float* __restrict__ out)       // [1]
{
    const int tid   = threadIdx.x;
    const int pair  = tid >> 2;        // 0..63 within block
    const int chunk = tid & 3;         // which 16-d slice
    const int n     = blockIdx.x * PAIRS_PER_BLOCK + pair;
    const int b     = blockIdx.y;

    const float* xp = x + ((size_t)b * N + n) * D + chunk * DC;  // 64 B slice
    const float* yp = y + (size_t)b * D * N + (size_t)(chunk * DC) * N + n;

    // Issue every load before any dependent math (MLP: 8 mem instrs in flight).
    float4 xv[4];
#pragma unroll
    for (int j = 0; j < 4; ++j)
        xv[j] = *reinterpret_cast<const float4*>(xp + 4 * j);

    float yv[DC];
#pragma unroll
    for (int d = 0; d < DC; ++d)
        yv[d] = yp[(size_t)d * N];     // lane-coalesced within each chunk group

    float acc = 0.0f;
#pragma unroll
    for (int j = 0; j < 4; ++j) {
        const float d0 = xv[j].x - yv[4 * j + 0];
        const float d1 = xv[j].y - yv[4 * j + 1];
        const float d2 = xv[j].z - yv[4 * j + 2];
        const float d3 = xv[j].w - yv[4 * j + 3];
        acc += d0 * d0 + d1 * d1 + d2 * d2 + d3 * d3;
    }

    // Sum the 4 chunks of this pair (lanes differing in bits 0..1).
    acc += __shfl_xor(acc, 1, 64);
    acc += __shfl_xor(acc, 2, 64);

    const float w = (n == 1 || n == 2) ? 1.5f : 1.0f;
    float v = (chunk == 0) ? w * __builtin_sqrtf(acc) : 0.0f;

    // Butterfly over the 16 group-leader lanes (bits 2..5); others contribute 0.
#pragma unroll
    for (int off = 4; off < 64; off <<= 1)
        v += __shfl_xor(v, off, 64);

    __shared__ float wsum[4];
    if ((tid & 63) == 0) wsum[tid >> 6] = v;
    __syncthreads();

    if (tid == 0) {
        const float s = (wsum[0] + wsum[1] + wsum[2] + wsum[3]) *
                        (1.0f / (float)(B * N));
        atomicAdd(out, s);
    }
}

extern "C" void kernel_launch(void* const* d_in, const int* in_sizes, int n_in,
                              void* d_out, int out_size, void* d_ws, size_t ws_size,
                              hipStream_t stream) {
    const float* x = (const float*)d_in[0];
    const float* y = (const float*)d_in[1];
    float* out = (float*)d_out;

    // d_out is re-poisoned to 0xAA before every timed launch; zero it first.
    hipMemsetAsync(out, 0, sizeof(float), stream);

    dim3 grid(N / PAIRS_PER_BLOCK, B);   // (128, 32) = 4096 blocks
    euclid_loss_kernel<<<grid, 256, 0, stream>>>(x, y, out);
}

// Round 3
// 147.393 us; speedup vs baseline: 1.1310x; 1.1310x over previous
//
#include <hip/hip_runtime.h>

// EuclideanLoss: loss = (1/(B*N)) * sum_{b,n} w_n * sqrt(sum_d (x[b,n,d]-y[b,d,n])^2)
// w_n = 1.5 for n in {1,2}. B=32, N=8192, D=64, fp32. Memory-bound: 128 MiB read.
//
// R2: R0 was MLP-starved (36 VGPRs, loads serialized in small batches);
// R1 broke y coalescing + compiler refused to hoist (24 VGPRs). Fix both:
// keep y wave-coalesced (all lanes of a wave share d, consecutive n -> 256 B/instr),
// split D=64 into 2 halves owned by wave pairs, exchange partial sums via LDS
// before sqrt. Per thread: 8 float4 x-loads + 32 scalar y-loads, ALL hoisted
// into regs (~64 data VGPRs) -> ~40 independent vmem instrs in flight.
// Grid 2048 blocks x 4 waves = 32 waves/CU demanded; ~80 VGPR -> 24/CU resident.

constexpr int B = 32;
constexpr int N = 8192;
constexpr int D = 64;
constexpr int HALF = D / 2;              // 32 d per wave
constexpr int NPB  = 128;                // n-values per block (2 wave-pairs)

__global__ __launch_bounds__(256) void euclid_loss_kernel(
    const float* __restrict__ x,   // [B, N, D]
    const float* __restrict__ y,   // [B, D, N]
    float* __restrict__ out)       // [1]
{
    const int tid    = threadIdx.x;
    const int wave   = tid >> 6;         // 0..3
    const int lane   = tid & 63;
    const int nchunk = wave >> 1;        // which 64-n group (0,1)
    const int half   = wave & 1;         // which d-half (0,1)
    const int n      = blockIdx.x * NPB + nchunk * 64 + lane;
    const int b      = blockIdx.y;

    const float* xp = x + ((size_t)b * N + n) * D + half * HALF;
    const float* yp = y + (size_t)b * D * N + (size_t)(half * HALF) * N + n;

    // Hoist ALL loads: 8 independent float4 (x) + 32 independent scalar (y).
    float4 xv[8];
#pragma unroll
    for (int j = 0; j < 8; ++j)
        xv[j] = *reinterpret_cast<const float4*>(xp + 4 * j);

    float yv[HALF];
#pragma unroll
    for (int d = 0; d < HALF; ++d)
        yv[d] = yp[(size_t)d * N];       // 256 B contiguous per wave instr

    float acc = 0.0f;
#pragma unroll
    for (int j = 0; j < 8; ++j) {
        const float d0 = xv[j].x - yv[4 * j + 0];
        const float d1 = xv[j].y - yv[4 * j + 1];
        const float d2 = xv[j].z - yv[4 * j + 2];
        const float d3 = xv[j].w - yv[4 * j + 3];
        acc += d0 * d0 + d1 * d1 + d2 * d2 + d3 * d3;
    }

    // Exchange d-half partial sums through LDS, combine before sqrt.
    __shared__ float part[2][NPB];
    part[half][nchunk * 64 + lane] = acc;    // 64 consecutive floats per wave: conflict-free
    __syncthreads();

    float v = 0.0f;
    if (tid < NPB) {
        const int n2 = blockIdx.x * NPB + tid;
        const float s = part[0][tid] + part[1][tid];
        const float w = (n2 == 1 || n2 == 2) ? 1.5f : 1.0f;
        v = w * __builtin_sqrtf(s);
    }

    // Waves 0,1 hold the 128 values (waves 2,3 have v=0): butterfly + LDS + atomic.
#pragma unroll
    for (int off = 32; off > 0; off >>= 1) v += __shfl_down(v, off, 64);

    __shared__ float wsum[4];
    if (lane == 0) wsum[wave] = v;
    __syncthreads();

    if (tid == 0) {
        const float s = (wsum[0] + wsum[1] + wsum[2] + wsum[3]) *
                        (1.0f / (float)(B * N));
        atomicAdd(out, s);
    }
}

extern "C" void kernel_launch(void* const* d_in, const int* in_sizes, int n_in,
                              void* d_out, int out_size, void* d_ws, size_t ws_size,
                              hipStream_t stream) {
    const float* x = (const float*)d_in[0];
    const float* y = (const float*)d_in[1];
    float* out = (float*)d_out;

    // d_out is re-poisoned to 0xAA before every timed launch; zero it first.
    hipMemsetAsync(out, 0, sizeof(float), stream);

    dim3 grid(N / NPB, B);               // (64, 32) = 2048 blocks
    euclid_loss_kernel<<<grid, 256, 0, stream>>>(x, y, out);
}